// Round 4
// baseline (397.866 us; speedup 1.0000x reference)
//
#include <hip/hip_runtime.h>
#include <hip/hip_bf16.h>
#include <stdint.h>

#define NROWS 8192
#define DDIM  256
#define SIGMA_INV 10.0f

#define BM 64
#define BN 64
#define NSPLIT 8                  // chunk = b&7 = XCD id (round-robin dispatch):
                                  // each XCD serves ONE j-slice (512KB embn +
                                  // 512KB vt, L2-resident). Grid 1024 = 768
                                  // resident at 3 blocks/CU + short tail.
#define JCHUNK (NROWS / NSPLIT)   // 1024
#define NITER  (JCHUNK / BN)      // 16
#define PSTR   72                 // pl row stride in halfs (144B, 16B-aligned)
#define KCHB   1056               // DMA chunk pitch: 1024B payload + 32B pad -> conflict-free reads

typedef __attribute__((ext_vector_type(8))) short bf16x8;
typedef __attribute__((ext_vector_type(4))) float f32x4;

__device__ inline unsigned short f2bf(float x) {
  __hip_bfloat16 h = __float2bfloat16(x);
  return *reinterpret_cast<unsigned short*>(&h);
}

__device__ inline void dma16(const void* g, void* l) {
  __builtin_amdgcn_global_load_lds(
      (const __attribute__((address_space(1))) unsigned int*)g,
      (__attribute__((address_space(3))) unsigned int*)l, 16, 0, 0);
}

// ---------------- K0: L2-normalize rows -> bf16 ----------------
__global__ __launch_bounds__(256) void normalize_k(const float* __restrict__ emb,
                                                   unsigned short* __restrict__ embn) {
  const int w = threadIdx.x >> 6, lane = threadIdx.x & 63;
  const int row = blockIdx.x * 4 + w;
  const float4* src = (const float4*)(emb + (size_t)row * DDIM);
  float4 v = src[lane];
  float ss = v.x * v.x + v.y * v.y + v.z * v.z + v.w * v.w;
  for (int off = 32; off >= 1; off >>= 1) ss += __shfl_xor(ss, off);
  const float sc = 1.0f / fmaxf(sqrtf(ss), 1e-12f);
  ushort4 o;
  o.x = f2bf(v.x * sc); o.y = f2bf(v.y * sc);
  o.z = f2bf(v.z * sc); o.w = f2bf(v.w * sc);
  ((ushort4*)(embn + (size_t)row * DDIM))[lane] = o;
}

// ---------------- K0b: emb[N][D] fp32 -> vt TILED bf16 ----------------
// vt layout: [jtile = j/64][d = 0..255][jj = j%64]  (32KB contiguous per j-tile)
__global__ __launch_bounds__(256) void transpose_k(const float* __restrict__ emb,
                                                   unsigned short* __restrict__ vt) {
  __shared__ float tile[64][65];
  const int r0 = blockIdx.x * 64, c0 = blockIdx.y * 64;
  const int tr = threadIdx.x >> 6, tc = threadIdx.x & 63;
  for (int i = 0; i < 16; ++i)
    tile[i * 4 + tr][tc] = emb[(size_t)(r0 + i * 4 + tr) * DDIM + c0 + tc];
  __syncthreads();
  unsigned short* dst = vt + (size_t)(r0 >> 6) * (DDIM * BN);   // jtile = r0/64
  for (int i = 0; i < 16; ++i)
    dst[(size_t)(c0 + i * 4 + tr) * BN + tc] = f2bf(tile[tc][i * 4 + tr]);
}

// ---------------- F: fused  S=Qn.Knt -> exp -> O += P.V, row sums ----------------
// ROUND-4 RESTRUCTURE: the loop is latency-bound at 2 waves/SIMD (rounds 0-3:
// all pipeline tweaks neutral; MFMA 16% + VALU 12% + LDS ~20%, nothing
// saturated). Fix = occupancy 2->3 waves/SIMD:
//  * min-live regs cut to ~160 via vfrag kk-split (only 8 V-frags = 32 VGPR
//    live at once; kk=1 batch issued after kk=0 frags die -> no overlap)
//  * launch_bounds(256,3): budget 512/3 ~= 168 >= min-live -> no spill
//    (round 1 spilled because min-live was 192 > 170)
//  * single kn buffer: LDS 42KB -> 3 blocks/CU (dbuf was neutral, round 3)
//  * grid 1024 (NSPLIT=8) so 3/CU can actually be filled (512 blocks can't)
// vmcnt ordering (in-order retirement!): every register load consumed before
// the next B1 must ISSUE BEFORE the DMA, else waiting on it drains the DMA.
// Order: B2 -> G2kk0 -> vfragB(8) -> DMA(t+1)(8) -> G2kk1(waits vmcnt<=8).
// Schedule per iter:
//   B1 __syncthreads            (DMA(t) drained; pl reads of t-1 drained)
//   G1: S = Q.Kn^T  from kn     (conflict-free padded-pitch b128 reads)
//   exp -> pl
//   vfragA issue (kk=0, 8 loads)
//   B2 RAW: lgkmcnt(0)+s_barrier (no vmem drain)
//   G2 kk=0                      (consumes vfragA)
//   vfragB issue (kk=1, 8 loads) (reuses vfragA's registers)
//   DMA(t+1) -> kn               (kn reads retired at B2; cover = G2kk1)
//   G2 kk=1                      (vmcnt<=8: DMA rides to next B1)
__global__ __launch_bounds__(256, 3) void fused_k(
    const unsigned short* __restrict__ embn,  // [N][D] bf16 normalized
    const unsigned short* __restrict__ vt,    // tiled [N/64][256][64] bf16
    float* __restrict__ out,                  // [N][D] fp32, pre-zeroed, atomic accum
    float* __restrict__ l_part)               // [N] fp32, pre-zeroed, atomic accum
{
  __shared__ char kn[32 * KCHB];              // 33 KB, padded DMA-staged K-tile
  __shared__ unsigned short pl[BM * PSTR];    // 9 KB, P transit

  const int tid = threadIdx.x;
  const int w = tid >> 6, lane = tid & 63;
  const int mg = w >> 1, dh = w & 1;          // m-group, d-half
  const int q = lane >> 4, c = lane & 15;
  const int chunk = blockIdx.x & 7;           // == XCD id
  const int mblk = blockIdx.x >> 3;
  const int row0 = mblk * BM + mg * 32;
  const int t0 = chunk * NITER;               // j-tile range [t0, t1)
  const int t1 = t0 + NITER;

  // Q fragments resident: A[m=lane&15][k=q*8+j]  (64 VGPR, reused all iters)
  bf16x8 qa[2][8];
  for (int mt = 0; mt < 2; ++mt)
    for (int k = 0; k < 8; ++k)
      qa[mt][k] = *(const bf16x8*)(embn + (size_t)(row0 + mt * 16 + c) * DDIM + k * 32 + q * 8);

  f32x4 oacc[2][8];
  for (int mt = 0; mt < 2; ++mt)
    for (int u = 0; u < 8; ++u) oacc[mt][u] = {0.f, 0.f, 0.f, 0.f};
  float lacc[2][4] = {};

  // prologue: stage first K-tile (32 x 1KB chunks at 1056B pitch, 8 per wave)
  {
    const char* src = (const char*)(embn + (size_t)t0 * BN * DDIM);
    for (int cc = 0; cc < 8; ++cc) {
      const int ch = w * 8 + cc;
      dma16(src + ch * 1024 + lane * 16, kn + ch * KCHB + lane * 16);
    }
  }

  // kn row r (512B payload) lives at (r>>1)*KCHB + (r&1)*512
  for (int it = t0; it < t1; ++it) {
    __syncthreads();  // B1: DMA(it) drained (vmcnt0); pl reads of it-1 drained

    // ---- G1: S[32x64] = Q . Kn^T ----
    f32x4 sacc[2][2];
    for (int mt = 0; mt < 2; ++mt)
      for (int nt = 0; nt < 2; ++nt) sacc[mt][nt] = {0.f, 0.f, 0.f, 0.f};
    const int rb0 = (dh * 16 + (c >> 1)) * KCHB + (c & 1) * 512;        // row dh*32+c
    const int rb1 = (dh * 16 + 8 + (c >> 1)) * KCHB + (c & 1) * 512;    // row dh*32+16+c
    for (int k = 0; k < 8; ++k) {
      bf16x8 b0 = *(const bf16x8*)(kn + rb0 + k * 64 + q * 16);
      bf16x8 b1 = *(const bf16x8*)(kn + rb1 + k * 64 + q * 16);
      for (int mt = 0; mt < 2; ++mt) {
        sacc[mt][0] = __builtin_amdgcn_mfma_f32_16x16x32_bf16(qa[mt][k], b0, sacc[mt][0], 0, 0, 0);
        sacc[mt][1] = __builtin_amdgcn_mfma_f32_16x16x32_bf16(qa[mt][k], b1, sacc[mt][1], 0, 0, 0);
      }
    }

    // exp (fixed shift 10; cos<=1 so logits<=10, softmax shift-invariant) + P + row sums
    for (int mt = 0; mt < 2; ++mt)
      for (int nt = 0; nt < 2; ++nt)
        for (int r = 0; r < 4; ++r) {
          const float p = __expf(fmaf(SIGMA_INV, sacc[mt][nt][r], -SIGMA_INV));
          lacc[mt][r] += p;
          // C/D layout: row = q*4+r, col = c
          pl[(mg * 32 + mt * 16 + q * 4 + r) * PSTR + dh * 32 + nt * 16 + c] = f2bf(p);
        }

    // vfragA: V frags for kk=0 (j0..j31 of this tile), 8 loads = 32 VGPR
    const unsigned short* vtile = vt + (size_t)it * (DDIM * BN);
    bf16x8 vfA[8];
    for (int u = 0; u < 8; ++u)
      vfA[u] = *(const bf16x8*)(vtile + (size_t)(dh * 128 + u * 16 + c) * BN + 0 * 32 + q * 8);

    // B2 RAW barrier: pl writes + kn ds_reads retired (lgkmcnt only).
    // NO vmem drain — vfragA rides through.
    __builtin_amdgcn_sched_barrier(0);
    asm volatile("s_waitcnt lgkmcnt(0)" ::: "memory");
    __builtin_amdgcn_sched_barrier(0);
    __builtin_amdgcn_s_barrier();
    __builtin_amdgcn_sched_barrier(0);

    // ---- G2 kk=0: O += P[:,0:32] . V[0:32,:] ----
    {
      bf16x8 ap0 = *(const bf16x8*)(pl + (mg * 32 + c) * PSTR + q * 8);
      bf16x8 ap1 = *(const bf16x8*)(pl + (mg * 32 + 16 + c) * PSTR + q * 8);
      for (int u = 0; u < 8; ++u) {
        oacc[0][u] = __builtin_amdgcn_mfma_f32_16x16x32_bf16(ap0, vfA[u], oacc[0][u], 0, 0, 0);
        oacc[1][u] = __builtin_amdgcn_mfma_f32_16x16x32_bf16(ap1, vfA[u], oacc[1][u], 0, 0, 0);
      }
    }
    __builtin_amdgcn_sched_barrier(0);  // keep vfragB below (register reuse of vfA)

    // vfragB: V frags for kk=1 — issued BEFORE the DMA so G2kk1's wait is
    // vmcnt<=8 (DMA stays in flight; in-order retirement).
    bf16x8 vfB[8];
    for (int u = 0; u < 8; ++u)
      vfB[u] = *(const bf16x8*)(vtile + (size_t)(dh * 128 + u * 16 + c) * BN + 1 * 32 + q * 8);

    // stage NEXT K-tile (kn reads all retired at B2); cover = G2 kk=1
    if (it + 1 < t1) {
      const char* src = (const char*)(embn + (size_t)(it + 1) * BN * DDIM);
      for (int cc = 0; cc < 8; ++cc) {
        const int ch = w * 8 + cc;
        dma16(src + ch * 1024 + lane * 16, kn + ch * KCHB + lane * 16);
      }
    }

    // ---- G2 kk=1: O += P[:,32:64] . V[32:64,:] ----
    {
      bf16x8 ap0 = *(const bf16x8*)(pl + (mg * 32 + c) * PSTR + 32 + q * 8);
      bf16x8 ap1 = *(const bf16x8*)(pl + (mg * 32 + 16 + c) * PSTR + 32 + q * 8);
      for (int u = 0; u < 8; ++u) {
        oacc[0][u] = __builtin_amdgcn_mfma_f32_16x16x32_bf16(ap0, vfB[u], oacc[0][u], 0, 0, 0);
        oacc[1][u] = __builtin_amdgcn_mfma_f32_16x16x32_bf16(ap1, vfB[u], oacc[1][u], 0, 0, 0);
      }
    }
  }

  // epilogue: row sums across the 16 c-lanes, then device atomics
  for (int mt = 0; mt < 2; ++mt)
    for (int r = 0; r < 4; ++r) {
      float s = lacc[mt][r];
      s += __shfl_xor(s, 1); s += __shfl_xor(s, 2);
      s += __shfl_xor(s, 4); s += __shfl_xor(s, 8);
      if (c == 0)
        atomicAdd(&l_part[row0 + mt * 16 + q * 4 + r], s);
    }
  for (int mt = 0; mt < 2; ++mt)
    for (int u = 0; u < 8; ++u)
      for (int r = 0; r < 4; ++r)
        atomicAdd(&out[(size_t)(row0 + mt * 16 + q * 4 + r) * DDIM + dh * 128 + u * 16 + c],
                  oacc[mt][u][r]);
}

// ---------------- K4: divide by row sums ----------------
__global__ __launch_bounds__(256) void finalize_k(float* __restrict__ out,
                                                  const float* __restrict__ l_part) {
  const int row = blockIdx.x, t = threadIdx.x;
  out[(size_t)row * DDIM + t] /= l_part[row];
}

extern "C" void kernel_launch(void* const* d_in, const int* in_sizes, int n_in,
                              void* d_out, int out_size, void* d_ws, size_t ws_size,
                              hipStream_t stream) {
  const float* emb = (const float*)d_in[0];
  float* out = (float*)d_out;
  char* ws = (char*)d_ws;
  // ws layout: embn 4MB | vt 4MB | l_part 32KB
  unsigned short* embn = (unsigned short*)ws;
  unsigned short* vt   = (unsigned short*)(ws + ((size_t)4 << 20));
  float* l_part        = (float*)(ws + ((size_t)8 << 20));

  hipMemsetAsync(out, 0, (size_t)NROWS * DDIM * sizeof(float), stream);
  hipMemsetAsync(l_part, 0, (size_t)NROWS * sizeof(float), stream);

  normalize_k<<<NROWS / 4, 256, 0, stream>>>(emb, embn);
  transpose_k<<<dim3(NROWS / 64, DDIM / 64), 256, 0, stream>>>(emb, vt);
  fused_k<<<(NROWS / BM) * NSPLIT, 256, 0, stream>>>(embn, vt, out, l_part);
  finalize_k<<<NROWS, 256, 0, stream>>>(out, l_part);
}

// Round 5
// 356.987 us; speedup vs baseline: 1.1145x; 1.1145x over previous
//
#include <hip/hip_runtime.h>
#include <hip/hip_bf16.h>
#include <stdint.h>

#define NROWS 8192
#define DDIM  256
#define SIGMA_INV 10.0f

#define BM 32                     // ROUND-5: halved so each wave owns 16 rows ->
                                  // qa 32 VGPR (was 64), oacc 32 AGPR (was 64).
                                  // Occupancy must come from NATURAL allocation:
                                  // launch_bounds min-waves hints are poison on
                                  // this codegen (rounds 1 & 4: (256,3) -> 84
                                  // VGPR + 400-650MB of spill traffic, 2x slower).
#define BN 64
#define NSPLIT 4                  // chunk = b&3: XCD b%8 serves exactly one 2MB
                                  // j-slice (L2-resident). Round-2 lesson: NSPLIT
                                  // must divide 8.
#define JCHUNK (NROWS / NSPLIT)   // 2048
#define NITER  (JCHUNK / BN)      // 32
#define PSTR   72                 // pl row stride in halfs (144B, 16B-aligned)
#define KCHB   1056               // DMA chunk pitch: 1024B payload + 32B pad -> conflict-free reads

typedef __attribute__((ext_vector_type(8))) short bf16x8;
typedef __attribute__((ext_vector_type(4))) float f32x4;

__device__ inline unsigned short f2bf(float x) {
  __hip_bfloat16 h = __float2bfloat16(x);
  return *reinterpret_cast<unsigned short*>(&h);
}

__device__ inline void dma16(const void* g, void* l) {
  __builtin_amdgcn_global_load_lds(
      (const __attribute__((address_space(1))) unsigned int*)g,
      (__attribute__((address_space(3))) unsigned int*)l, 16, 0, 0);
}

// ---------------- K0: L2-normalize rows -> bf16 ----------------
__global__ __launch_bounds__(256) void normalize_k(const float* __restrict__ emb,
                                                   unsigned short* __restrict__ embn) {
  const int w = threadIdx.x >> 6, lane = threadIdx.x & 63;
  const int row = blockIdx.x * 4 + w;
  const float4* src = (const float4*)(emb + (size_t)row * DDIM);
  float4 v = src[lane];
  float ss = v.x * v.x + v.y * v.y + v.z * v.z + v.w * v.w;
  for (int off = 32; off >= 1; off >>= 1) ss += __shfl_xor(ss, off);
  const float sc = 1.0f / fmaxf(sqrtf(ss), 1e-12f);
  ushort4 o;
  o.x = f2bf(v.x * sc); o.y = f2bf(v.y * sc);
  o.z = f2bf(v.z * sc); o.w = f2bf(v.w * sc);
  ((ushort4*)(embn + (size_t)row * DDIM))[lane] = o;
}

// ---------------- K0b: emb[N][D] fp32 -> vt TILED bf16 ----------------
// vt layout: [jtile = j/64][d = 0..255][jj = j%64]  (32KB contiguous per j-tile)
__global__ __launch_bounds__(256) void transpose_k(const float* __restrict__ emb,
                                                   unsigned short* __restrict__ vt) {
  __shared__ float tile[64][65];
  const int r0 = blockIdx.x * 64, c0 = blockIdx.y * 64;
  const int tr = threadIdx.x >> 6, tc = threadIdx.x & 63;
  for (int i = 0; i < 16; ++i)
    tile[i * 4 + tr][tc] = emb[(size_t)(r0 + i * 4 + tr) * DDIM + c0 + tc];
  __syncthreads();
  unsigned short* dst = vt + (size_t)(r0 >> 6) * (DDIM * 64);   // jtile = r0/64
  for (int i = 0; i < 16; ++i)
    dst[(size_t)(c0 + i * 4 + tr) * 64 + tc] = f2bf(tile[tc][i * 4 + tr]);
}

// ---------------- F: fused  S=Qn.Knt -> exp -> O += P.V, row sums ----------------
// grid = 256 mblk x 4 chunks = 1024 blocks, 256 threads (4 waves).
// Wave (mg=w>>1, dh=w&1) owns: G1 S[16 rows (mg)][32 cols (dh)],
// G2 O[16 rows (mg)][128 d-cols (dh)]. Per-wave regs ~ qa32 + vf32 + sacc8
// + oacc32(acc) + addr ~= 145 total -> 3 waves/SIMD from NATURAL allocation
// (cap 170). LDS 38.4KB -> not binding. NO launch_bounds min-waves (see BM note).
// Schedule per iter (2 barriers, proven in rounds 0-4):
//   B1 __syncthreads             (DMA(t) drained; pl reads of t-1 drained)
//   G1: S = Q.Kn^T  from kn      (conflict-free padded-pitch b128 reads)
//   exp -> pl
//   vfragA issue (kk=0, 8 loads)
//   B2 RAW: lgkmcnt(0)+s_barrier (no vmem drain; vfragA rides through)
//   G2 kk=0
//   vfragB issue (kk=1)          (reuses vfragA registers)
//   DMA(t+1) -> kn               (kn reads retired at B2; must issue AFTER all
//                                 register loads consumed before next B1)
//   G2 kk=1                      (waits vmcnt<=8; DMA rides to next B1)
__global__ __launch_bounds__(256) void fused_k(
    const unsigned short* __restrict__ embn,  // [N][D] bf16 normalized
    const unsigned short* __restrict__ vt,    // tiled [N/64][256][64] bf16
    float* __restrict__ out,                  // [N][D] fp32, pre-zeroed, atomic accum
    float* __restrict__ l_part)               // [N] fp32, pre-zeroed, atomic accum
{
  __shared__ char kn[32 * KCHB];              // 33 KB, padded DMA-staged K-tile
  __shared__ unsigned short pl[BM * PSTR];    // 4.6 KB, P transit

  const int tid = threadIdx.x;
  const int w = tid >> 6, lane = tid & 63;
  const int mg = w >> 1, dh = w & 1;          // m-group (16 rows), d-half / s-col-half
  const int q = lane >> 4, c = lane & 15;
  const int chunk = blockIdx.x & 3;
  const int mblk = blockIdx.x >> 2;
  const int row0 = mblk * BM + mg * 16;       // this wave's 16 rows
  const int t0 = chunk * NITER;               // j-tile range [t0, t1)
  const int t1 = t0 + NITER;

  // Q fragments resident: A[m=c][k=q*8+j]  (32 VGPR)
  bf16x8 qa[8];
  for (int k = 0; k < 8; ++k)
    qa[k] = *(const bf16x8*)(embn + (size_t)(row0 + c) * DDIM + k * 32 + q * 8);

  f32x4 oacc[8];                              // 32 acc regs
  for (int u = 0; u < 8; ++u) oacc[u] = {0.f, 0.f, 0.f, 0.f};
  float lacc[4] = {};

  // prologue: stage first K-tile (32 x 1KB chunks at 1056B pitch, 8 per wave)
  {
    const char* src = (const char*)(embn + (size_t)t0 * BN * DDIM);
    for (int cc = 0; cc < 8; ++cc) {
      const int ch = w * 8 + cc;
      dma16(src + ch * 1024 + lane * 16, kn + ch * KCHB + lane * 16);
    }
  }

  // kn row r (512B payload) lives at (r>>1)*KCHB + (r&1)*512
  for (int it = t0; it < t1; ++it) {
    __syncthreads();  // B1: DMA(it) drained (vmcnt0); pl reads of it-1 drained

    // ---- G1: S[16x32] = Q . Kn^T (this wave: rows mg*16+, cols dh*32+) ----
    f32x4 sacc[2];
    sacc[0] = {0.f, 0.f, 0.f, 0.f};
    sacc[1] = {0.f, 0.f, 0.f, 0.f};
    const int rb0 = (dh * 16 + (c >> 1)) * KCHB + (c & 1) * 512;        // kn row dh*32+c
    const int rb1 = (dh * 16 + 8 + (c >> 1)) * KCHB + (c & 1) * 512;    // kn row dh*32+16+c
    for (int k = 0; k < 8; ++k) {
      bf16x8 b0 = *(const bf16x8*)(kn + rb0 + k * 64 + q * 16);
      bf16x8 b1 = *(const bf16x8*)(kn + rb1 + k * 64 + q * 16);
      sacc[0] = __builtin_amdgcn_mfma_f32_16x16x32_bf16(qa[k], b0, sacc[0], 0, 0, 0);
      sacc[1] = __builtin_amdgcn_mfma_f32_16x16x32_bf16(qa[k], b1, sacc[1], 0, 0, 0);
    }

    // exp (fixed shift 10; cos<=1 so logits<=10, softmax shift-invariant) + P + row sums
    for (int nt = 0; nt < 2; ++nt)
      for (int r = 0; r < 4; ++r) {
        const float p = __expf(fmaf(SIGMA_INV, sacc[nt][r], -SIGMA_INV));
        lacc[r] += p;
        // C/D layout: row = q*4+r, col = c
        pl[(mg * 16 + q * 4 + r) * PSTR + dh * 32 + nt * 16 + c] = f2bf(p);
      }

    // vfragA: V frags for kk=0, 8 loads = 32 VGPR (sacc now dead -> reuse)
    const unsigned short* vtile = vt + (size_t)it * (DDIM * BN);
    bf16x8 vfA[8];
    for (int u = 0; u < 8; ++u)
      vfA[u] = *(const bf16x8*)(vtile + (size_t)(dh * 128 + u * 16 + c) * BN + q * 8);

    // B2 RAW barrier: pl writes + kn ds_reads retired (lgkmcnt only).
    // NO vmem drain — vfragA rides through.
    __builtin_amdgcn_sched_barrier(0);
    asm volatile("s_waitcnt lgkmcnt(0)" ::: "memory");
    __builtin_amdgcn_sched_barrier(0);
    __builtin_amdgcn_s_barrier();
    __builtin_amdgcn_sched_barrier(0);

    // ---- G2 kk=0: O += P[:,0:32] . V[0:32,:] ----
    {
      bf16x8 ap = *(const bf16x8*)(pl + (mg * 16 + c) * PSTR + q * 8);
      for (int u = 0; u < 8; ++u)
        oacc[u] = __builtin_amdgcn_mfma_f32_16x16x32_bf16(ap, vfA[u], oacc[u], 0, 0, 0);
    }
    __builtin_amdgcn_sched_barrier(0);  // keep vfragB below (register reuse of vfA)

    // vfragB: V frags for kk=1 — issued BEFORE the DMA so G2kk1's wait is
    // vmcnt<=8 (DMA stays in flight; in-order retirement).
    bf16x8 vfB[8];
    for (int u = 0; u < 8; ++u)
      vfB[u] = *(const bf16x8*)(vtile + (size_t)(dh * 128 + u * 16 + c) * BN + 32 + q * 8);

    // stage NEXT K-tile (kn reads all retired at B2); cover = G2 kk=1
    if (it + 1 < t1) {
      const char* src = (const char*)(embn + (size_t)(it + 1) * BN * DDIM);
      for (int cc = 0; cc < 8; ++cc) {
        const int ch = w * 8 + cc;
        dma16(src + ch * 1024 + lane * 16, kn + ch * KCHB + lane * 16);
      }
    }

    // ---- G2 kk=1: O += P[:,32:64] . V[32:64,:] ----
    {
      bf16x8 ap = *(const bf16x8*)(pl + (mg * 16 + c) * PSTR + 32 + q * 8);
      for (int u = 0; u < 8; ++u)
        oacc[u] = __builtin_amdgcn_mfma_f32_16x16x32_bf16(ap, vfB[u], oacc[u], 0, 0, 0);
    }
  }

  // epilogue: row sums across the 16 c-lanes, then device atomics
  for (int r = 0; r < 4; ++r) {
    float s = lacc[r];
    s += __shfl_xor(s, 1); s += __shfl_xor(s, 2);
    s += __shfl_xor(s, 4); s += __shfl_xor(s, 8);
    if (c == 0)
      atomicAdd(&l_part[row0 + q * 4 + r], s);
  }
  for (int u = 0; u < 8; ++u)
    for (int r = 0; r < 4; ++r)
      atomicAdd(&out[(size_t)(row0 + q * 4 + r) * DDIM + dh * 128 + u * 16 + c],
                oacc[u][r]);
}

// ---------------- K4: divide by row sums ----------------
__global__ __launch_bounds__(256) void finalize_k(float* __restrict__ out,
                                                  const float* __restrict__ l_part) {
  const int row = blockIdx.x, t = threadIdx.x;
  out[(size_t)row * DDIM + t] /= l_part[row];
}

extern "C" void kernel_launch(void* const* d_in, const int* in_sizes, int n_in,
                              void* d_out, int out_size, void* d_ws, size_t ws_size,
                              hipStream_t stream) {
  const float* emb = (const float*)d_in[0];
  float* out = (float*)d_out;
  char* ws = (char*)d_ws;
  // ws layout: embn 4MB | vt 4MB | l_part 32KB
  unsigned short* embn = (unsigned short*)ws;
  unsigned short* vt   = (unsigned short*)(ws + ((size_t)4 << 20));
  float* l_part        = (float*)(ws + ((size_t)8 << 20));

  hipMemsetAsync(out, 0, (size_t)NROWS * DDIM * sizeof(float), stream);
  hipMemsetAsync(l_part, 0, (size_t)NROWS * sizeof(float), stream);

  normalize_k<<<NROWS / 4, 256, 0, stream>>>(emb, embn);
  transpose_k<<<dim3(NROWS / 64, DDIM / 64), 256, 0, stream>>>(emb, vt);
  fused_k<<<(NROWS / BM) * NSPLIT, 256, 0, stream>>>(embn, vt, out, l_part);
  finalize_k<<<NROWS, 256, 0, stream>>>(out, l_part);
}

// Round 6
// 245.854 us; speedup vs baseline: 1.6183x; 1.4520x over previous
//
#include <hip/hip_runtime.h>
#include <hip/hip_bf16.h>
#include <stdint.h>

#define NROWS 8192
#define DDIM  256
#define SIGMA_INV 10.0f

#define BM 64                     // round-5 lesson: shrinking BM halves per-iter
                                  // work but T_iter stays ~const -> 1.7x SLOWER.
                                  // T_iter tracks BYTES STAGED, not flops/waves.
#define BN 64
#define NSPLIT 4                  // chunk=b&3, XCD=b%8 -> each XCD serves ONE 2MB
                                  // j-slice (L2-resident). Round-2 lesson.
#define JCHUNK (NROWS / NSPLIT)   // 2048
#define NITER  (JCHUNK / BN)      // 32
#define PSTR   72                 // pl row stride in halfs (144B, 16B-aligned)
#define KCHB   1056               // DMA chunk pitch: 1024B payload + 32B pad
#define KNSZ   (32 * KCHB)        // one K-tile buffer: 33792 B

typedef __attribute__((ext_vector_type(8))) short bf16x8;
typedef __attribute__((ext_vector_type(4))) float f32x4;

__device__ inline unsigned short f2bf(float x) {
  __hip_bfloat16 h = __float2bfloat16(x);
  return *reinterpret_cast<unsigned short*>(&h);
}

__device__ inline void dma16(const void* g, void* l) {
  __builtin_amdgcn_global_load_lds(
      (const __attribute__((address_space(1))) unsigned int*)g,
      (__attribute__((address_space(3))) unsigned int*)l, 16, 0, 0);
}

// ---------------- K0: L2-normalize rows -> bf16 ----------------
__global__ __launch_bounds__(256) void normalize_k(const float* __restrict__ emb,
                                                   unsigned short* __restrict__ embn) {
  const int w = threadIdx.x >> 6, lane = threadIdx.x & 63;
  const int row = blockIdx.x * 4 + w;
  const float4* src = (const float4*)(emb + (size_t)row * DDIM);
  float4 v = src[lane];
  float ss = v.x * v.x + v.y * v.y + v.z * v.z + v.w * v.w;
  for (int off = 32; off >= 1; off >>= 1) ss += __shfl_xor(ss, off);
  const float sc = 1.0f / fmaxf(sqrtf(ss), 1e-12f);
  ushort4 o;
  o.x = f2bf(v.x * sc); o.y = f2bf(v.y * sc);
  o.z = f2bf(v.z * sc); o.w = f2bf(v.w * sc);
  ((ushort4*)(embn + (size_t)row * DDIM))[lane] = o;
}

// ---------------- K0b: emb[N][D] fp32 -> vt TILED bf16 ----------------
// vt layout: [jtile = j/64][d = 0..255][jj = j%64]  (32KB contiguous per j-tile)
__global__ __launch_bounds__(256) void transpose_k(const float* __restrict__ emb,
                                                   unsigned short* __restrict__ vt) {
  __shared__ float tile[64][65];
  const int r0 = blockIdx.x * 64, c0 = blockIdx.y * 64;
  const int tr = threadIdx.x >> 6, tc = threadIdx.x & 63;
  for (int i = 0; i < 16; ++i)
    tile[i * 4 + tr][tc] = emb[(size_t)(r0 + i * 4 + tr) * DDIM + c0 + tc];
  __syncthreads();
  unsigned short* dst = vt + (size_t)(r0 >> 6) * (DDIM * 64);   // jtile = r0/64
  for (int i = 0; i < 16; ++i)
    dst[(size_t)(c0 + i * 4 + tr) * 64 + tc] = f2bf(tile[tc][i * 4 + tr]);
}

// ---------------- F: fused  S=Qn.Knt -> exp -> O += P.V, row sums ----------------
// grid = 128 mblk x 4 chunks = 512 blocks = 2/CU. Round-3 base (dbuf kn, raw B2,
// tiled vt) + ROUND-6 CHANGE: ITERATION SKEW.
//   Without skew, all 64 resident blocks of an XCD march through the j-tiles in
//   LOCKSTEP: every block DMAs the same 32KB kn tile and reads the same 32KB vt
//   tile at the same instant -> L2 line/bank camping on ~64KB of hot lines.
//   Cross-round evidence (R0-R5: T_iter ~ const ~ bytes staged; all latency /
//   occupancy / pipelining levers neutral) says L2 delivery is the limiter.
//   Skew: block mblk starts at tile t0 + (5*mblk mod 32) and wraps. 32 distinct
//   phases across the 64 blocks of an XCD; same-CU pairs (mblk, mblk+64) keep
//   the SAME phase so they still share L1/L2 lines. Bytes unchanged.
__global__ __launch_bounds__(256, 2) void fused_k(
    const unsigned short* __restrict__ embn,  // [N][D] bf16 normalized
    const unsigned short* __restrict__ vt,    // tiled [N/64][256][64] bf16
    float* __restrict__ out,                  // [N][D] fp32, pre-zeroed, atomic accum
    float* __restrict__ l_part)               // [N] fp32, pre-zeroed, atomic accum
{
  __shared__ char kn[2 * KNSZ];               // 66 KB, double-buffered DMA K-tiles
  __shared__ unsigned short pl[BM * PSTR];    // 9 KB, P transit

  const int tid = threadIdx.x;
  const int w = tid >> 6, lane = tid & 63;
  const int mg = w >> 1, dh = w & 1;          // m-group, d-half
  const int q = lane >> 4, c = lane & 15;
  const int chunk = blockIdx.x & 3;
  const int mblk = blockIdx.x >> 2;
  const int row0 = mblk * BM + mg * 32;
  const int t0 = chunk * NITER;               // j-tile range [t0, t0+NITER)
  const int st = (mblk * 5) & (NITER - 1);    // skew phase (coprime multiplier)

  // Q fragments resident: A[m=lane&15][k=q*8+j]
  bf16x8 qa[2][8];
  for (int mt = 0; mt < 2; ++mt)
    for (int k = 0; k < 8; ++k)
      qa[mt][k] = *(const bf16x8*)(embn + (size_t)(row0 + mt * 16 + c) * DDIM + k * 32 + q * 8);

  f32x4 oacc[2][8];
  for (int mt = 0; mt < 2; ++mt)
    for (int u = 0; u < 8; ++u) oacc[mt][u] = {0.f, 0.f, 0.f, 0.f};
  float lacc[2][4] = {};

  // prologue: stage first (skewed) K-tile into kn[0]
  {
    const int it0 = t0 + st;
    const char* src = (const char*)(embn + (size_t)it0 * BN * DDIM);
    for (int cc = 0; cc < 8; ++cc) {
      const int ch = w * 8 + cc;
      dma16(src + ch * 1024 + lane * 16, kn + ch * KCHB + lane * 16);
    }
  }

  // kn row r (512B payload) lives at bsel*KNSZ + (r>>1)*KCHB + (r&1)*512
  for (int s = 0; s < NITER; ++s) {
    const int it = t0 + ((st + s) & (NITER - 1));   // skewed, wrapped tile index
    const int bsel = s & 1;
    const char* knb = kn + bsel * KNSZ;

    __syncthreads();  // B1: vmcnt(0)+lgkmcnt(0)+barrier. DMA(s) (issued top of
                      // iter s-1 / prologue) drained with full-iter cover;
                      // pl reads of iter s-1 drained.

    // stage NEXT K-tile into the other buffer NOW: its readers (G1 of s-1)
    // retired at s-1's B2; covered by the entirety of iter s.
    if (s + 1 < NITER) {
      const int itn = t0 + ((st + s + 1) & (NITER - 1));
      const char* src = (const char*)(embn + (size_t)itn * BN * DDIM);
      char* dst = kn + (bsel ^ 1) * KNSZ;
      for (int cc = 0; cc < 8; ++cc) {
        const int ch = w * 8 + cc;
        dma16(src + ch * 1024 + lane * 16, dst + ch * KCHB + lane * 16);
      }
    }

    // ---- G1: S[32x64] = Q . Kn^T (kn reads conflict-free via padded pitch) ----
    f32x4 sacc[2][2];
    for (int mt = 0; mt < 2; ++mt)
      for (int nt = 0; nt < 2; ++nt) sacc[mt][nt] = {0.f, 0.f, 0.f, 0.f};
    const int rb0 = (dh * 16 + (c >> 1)) * KCHB + (c & 1) * 512;        // row dh*32+c
    const int rb1 = (dh * 16 + 8 + (c >> 1)) * KCHB + (c & 1) * 512;    // row dh*32+16+c
    for (int k = 0; k < 8; ++k) {
      bf16x8 b0 = *(const bf16x8*)(knb + rb0 + k * 64 + q * 16);
      bf16x8 b1 = *(const bf16x8*)(knb + rb1 + k * 64 + q * 16);
      for (int mt = 0; mt < 2; ++mt) {
        sacc[mt][0] = __builtin_amdgcn_mfma_f32_16x16x32_bf16(qa[mt][k], b0, sacc[mt][0], 0, 0, 0);
        sacc[mt][1] = __builtin_amdgcn_mfma_f32_16x16x32_bf16(qa[mt][k], b1, sacc[mt][1], 0, 0, 0);
      }
    }

    // prefetch V frags into registers from the CONTIGUOUS 32KB j-tile.
    const unsigned short* vtile = vt + (size_t)it * (DDIM * BN);
    bf16x8 vfrag[2][8];
    for (int kk = 0; kk < 2; ++kk)
      for (int u = 0; u < 8; ++u)
        vfrag[kk][u] = *(const bf16x8*)(vtile + (size_t)(dh * 128 + u * 16 + c) * BN + kk * 32 + q * 8);

    // exp (fixed shift 10; cos<=1 so logits<=10, softmax shift-invariant) + P + row sums
    for (int mt = 0; mt < 2; ++mt)
      for (int nt = 0; nt < 2; ++nt)
        for (int r = 0; r < 4; ++r) {
          const float p = __expf(fmaf(SIGMA_INV, sacc[mt][nt][r], -SIGMA_INV));
          lacc[mt][r] += p;
          // C/D layout: row = q*4+r, col = c
          pl[(mg * 32 + mt * 16 + q * 4 + r) * PSTR + dh * 32 + nt * 16 + c] = f2bf(p);
        }

    // B2 RAW barrier: pl writes + kn ds_reads retired (lgkmcnt only).
    // Deliberately NO vmcnt drain — vfrag + DMA(s+1) stay outstanding.
    __builtin_amdgcn_sched_barrier(0);
    asm volatile("s_waitcnt lgkmcnt(0)" ::: "memory");
    __builtin_amdgcn_sched_barrier(0);
    __builtin_amdgcn_s_barrier();
    __builtin_amdgcn_sched_barrier(0);

    // ---- G2: O[32x128] += P[32x64] . V[64x128] ----
    for (int kk = 0; kk < 2; ++kk) {
      bf16x8 ap0 = *(const bf16x8*)(pl + (mg * 32 + c) * PSTR + kk * 32 + q * 8);
      bf16x8 ap1 = *(const bf16x8*)(pl + (mg * 32 + 16 + c) * PSTR + kk * 32 + q * 8);
      for (int u = 0; u < 8; ++u) {
        oacc[0][u] = __builtin_amdgcn_mfma_f32_16x16x32_bf16(ap0, vfrag[kk][u], oacc[0][u], 0, 0, 0);
        oacc[1][u] = __builtin_amdgcn_mfma_f32_16x16x32_bf16(ap1, vfrag[kk][u], oacc[1][u], 0, 0, 0);
      }
    }
  }

  // epilogue: row sums across the 16 c-lanes, then device atomics
  for (int mt = 0; mt < 2; ++mt)
    for (int r = 0; r < 4; ++r) {
      float s = lacc[mt][r];
      s += __shfl_xor(s, 1); s += __shfl_xor(s, 2);
      s += __shfl_xor(s, 4); s += __shfl_xor(s, 8);
      if (c == 0)
        atomicAdd(&l_part[row0 + mt * 16 + q * 4 + r], s);
    }
  for (int mt = 0; mt < 2; ++mt)
    for (int u = 0; u < 8; ++u)
      for (int r = 0; r < 4; ++r)
        atomicAdd(&out[(size_t)(row0 + mt * 16 + q * 4 + r) * DDIM + dh * 128 + u * 16 + c],
                  oacc[mt][u][r]);
}

// ---------------- K4: divide by row sums ----------------
__global__ __launch_bounds__(256) void finalize_k(float* __restrict__ out,
                                                  const float* __restrict__ l_part) {
  const int row = blockIdx.x, t = threadIdx.x;
  out[(size_t)row * DDIM + t] /= l_part[row];
}

extern "C" void kernel_launch(void* const* d_in, const int* in_sizes, int n_in,
                              void* d_out, int out_size, void* d_ws, size_t ws_size,
                              hipStream_t stream) {
  const float* emb = (const float*)d_in[0];
  float* out = (float*)d_out;
  char* ws = (char*)d_ws;
  // ws layout: embn 4MB | vt 4MB | l_part 32KB
  unsigned short* embn = (unsigned short*)ws;
  unsigned short* vt   = (unsigned short*)(ws + ((size_t)4 << 20));
  float* l_part        = (float*)(ws + ((size_t)8 << 20));

  hipMemsetAsync(out, 0, (size_t)NROWS * DDIM * sizeof(float), stream);
  hipMemsetAsync(l_part, 0, (size_t)NROWS * sizeof(float), stream);

  normalize_k<<<NROWS / 4, 256, 0, stream>>>(emb, embn);
  transpose_k<<<dim3(NROWS / 64, DDIM / 64), 256, 0, stream>>>(emb, vt);
  fused_k<<<(NROWS / BM) * NSPLIT, 256, 0, stream>>>(embn, vt, out, l_part);
  finalize_k<<<NROWS, 256, 0, stream>>>(out, l_part);
}